// Round 15
// baseline (207.318 us; speedup 1.0000x reference)
//
#include <hip/hip_runtime.h>

// Problem constants
#define BB   128
#define DD   2048
#define NN   2048
#define LL   4
#define OUTN 1024
#define JBQ  32                // 16-k groups per K-quarter (512 k / quarter)
#define NDIG 5                 // unsigned-mode planes (base-128, bias 2^34)
#define NSGN 4                 // signed-mode planes (base-256, scale 2^-28)

#define NWDIG 3072             // wdig blocks: 3 layers x 32 nchunk x 32 kchunk
#define NG0   1024             // At blocks: DD*BB/256
#define NCSR  4                // inverse-map builds (axon1..3, out_idx)

// Wd layout (R13): [l][nsup:64][kc:32][j:5][cc:32][kk:64]
#define WD_NSUP 327680
#define WD_KC   10240
#define WD_J    2048

typedef double double4v __attribute__((ext_vector_type(4)));
typedef int    int4v    __attribute__((ext_vector_type(4)));
typedef char   char4v   __attribute__((ext_vector_type(4)));
typedef char   char16v  __attribute__((ext_vector_type(16)));

// ---------------------------------------------------------------------------
// Runtime i8-MFMA signedness probe (R14-proven: gfx950 came back SIGNED).
// A bytes all 0xFF, B one-hot => D = -1 (signed) / 255 (unsigned).
// ---------------------------------------------------------------------------
__device__ __forceinline__ int i8_probe_signed()
{
    const int lane = threadIdx.x & 63;
    const int hot  = ((lane >> 4) == 0) ? 1 : 0;
    int4v aFF  = {-1, -1, -1, -1};         // every byte 0xFF
    int4v oneh = {hot, 0, 0, 0};
    int4v d    = {0, 0, 0, 0};
    d = __builtin_amdgcn_mfma_i32_16x16x64_i8(aFF, oneh, d, 0, 0, 0);
    return d[0] < 0;
}

// ---------------------------------------------------------------------------
// PREP kernel (one launch): blockIdx-partitioned independent producers.
//  [0, NWDIG)      : W digitization, R15 BIT-TRICK form (signed mode):
//                    V = rintf(W*2^28f)  (exact: *2^28 is an exponent shift)
//                    X = (V + 0x80808080) ^ 0x80808080
//                    plane j = byte j of X   (balanced base-256 digits,
//                    provably bit-identical to R14's fp64 carry chain;
//                    ~5 fp32/int ops per element vs ~30 half-rate fp64 ops
//                    -- prep was ~40us vs ~16us traffic floor, VALU-bound).
//                    Unsigned fallback: R12/R13-proven biased path.
//  [NWDIG, +NG0)   : At TILED [kc:32][b:128][kk:64]
//  [NWDIG+NG0, +4) : CSR inverse maps (axon1..3, out_idx)
// ---------------------------------------------------------------------------
__global__ __launch_bounds__(256) void prep_kernel(
    const float* __restrict__ W1,      // W + DP (layers 1..3)
    const float* __restrict__ x,
    const int*   __restrict__ axon,
    const int*   __restrict__ oidx,
    signed char* __restrict__ Wd,
    float*       __restrict__ At,
    int*         __restrict__ off,     // [4][2052]
    int*         __restrict__ lst)     // [4][2048]
{
    __shared__ int hist[2048];
    __shared__ int part[256];

    const int t  = threadIdx.x;
    const int bk = blockIdx.x;
    const size_t DP = (size_t)NN * DD;

    if (bk < NWDIG) {
        // ---- W digitization, wide stores, dual encoding ----
        const int l   = bk >> 10;            // 1024 blocks per layer
        const int rem = bk & 1023;
        const int nc  = rem >> 5;            // n-chunk 0..31 (64 rows each)
        const int kc  = rem & 31;            // k-chunk 0..31 (64 cols each)
        const int n   = nc * 64 + (t >> 2);
        const int k   = kc * 64 + (t & 3) * 16;

        const float* wp = W1 + (size_t)l * DP + (size_t)n * DD + k;
        float wv[16];
        #pragma unroll
        for (int p = 0; p < 4; ++p) {
            float4 w = *(const float4*)(wp + 4 * p);
            wv[4 * p + 0] = w.x; wv[4 * p + 1] = w.y;
            wv[4 * p + 2] = w.z; wv[4 * p + 3] = w.w;
        }
        signed char* base = Wd + (size_t)l * 5 * DP
                          + (size_t)(n >> 5) * WD_NSUP + (size_t)kc * WD_KC
                          + (n & 31) * 64 + (k & 63);

        const int sgn = i8_probe_signed();
        if (sgn) {
            // balanced base-256 digits via add/xor bit trick (R15)
            int X[16];
            #pragma unroll
            for (int e = 0; e < 16; ++e) {
                int V = (int)rintf(wv[e] * 0x1p28f);   // exact, == fp64 path
                X[e] = (int)(((unsigned)V + 0x80808080u) ^ 0x80808080u);
            }
            #pragma unroll
            for (int j = 0; j < NSGN; ++j) {
                char16v p;
                #pragma unroll
                for (int e = 0; e < 16; ++e)
                    p[e] = (char)((X[e] >> (8 * j)) & 255);
                *(char16v*)(base + (size_t)j * WD_J) = p;
            }
        } else {
            // unsigned-safe biased base-128, 5 planes (R12/R13-proven)
            unsigned long long V[16];
            #pragma unroll
            for (int e = 0; e < 16; ++e)
                V[e] = (unsigned long long)(__double2ll_rn((double)wv[e] * 0x1p33)
                                            + (1LL << 34));
            #pragma unroll
            for (int j = 0; j < NDIG; ++j) {
                char16v p;
                #pragma unroll
                for (int e = 0; e < 16; ++e)
                    p[e] = (char)((V[e] >> (7 * j)) & 127);
                *(char16v*)(base + (size_t)j * WD_J) = p;
            }
        }
        return;
    }
    if (bk < NWDIG + NG0) {
        // ---- layer-0 gather into TILED At (R10-proven) ----
        int i = (bk - NWDIG) * 256 + t;            // over BB*DD
        int b = i >> 11;
        int k = i & (DD - 1);
        At[(size_t)(k >> 6) * 8192 + b * 64 + (k & 63)] = x[b * DD + axon[k]];
        return;
    }
    // ---- CSR inverse-map build (4 blocks, R7-proven) ----
    {
        const int m   = bk - (NWDIG + NG0);
        const int* ip = (m < 3) ? (axon + (size_t)(m + 1) * DD) : oidx;
        const int cnt = (m < 3) ? DD : OUTN;
        int* offG = off + m * 2052;
        int* lstG = lst + m * 2048;

        for (int i = t; i < 2048; i += 256) hist[i] = 0;
        __syncthreads();
        for (int e = t; e < cnt; e += 256) atomicAdd(&hist[ip[e]], 1);
        __syncthreads();

        const int b0 = t * 8;
        int s = 0;
        #pragma unroll
        for (int i = 0; i < 8; ++i) s += hist[b0 + i];
        part[t] = s;
        __syncthreads();
        for (int d = 1; d < 256; d <<= 1) {
            int v = (t >= d) ? part[t - d] : 0;
            __syncthreads();
            part[t] += v;
            __syncthreads();
        }
        int base = part[t] - s;
        #pragma unroll
        for (int i = 0; i < 8; ++i) {
            int h = hist[b0 + i];
            offG[b0 + i] = base;
            hist[b0 + i] = base;
            base += h;
        }
        if (t == 255) offG[2048] = base;
        __syncthreads();
        for (int e = t; e < cnt; e += 256) {
            int n = ip[e];
            int pos = atomicAdd(&hist[n], 1);
            lstG[pos] = e;
        }
    }
}

// ---------------------------------------------------------------------------
// Layer 0, fp64 MFMA (R10-proven interior; ~45us control, untouched).
// ---------------------------------------------------------------------------
__global__ __launch_bounds__(256, 4) void layer0_kernel(
    const float* __restrict__ Atile,  // [kc:32][b:128][kk:64] fp32
    const float* __restrict__ Wl,     // layer-0 W [n][k]
    const float* __restrict__ thr,
    const int*   __restrict__ Tptr,
    const int* __restrict__ goff, const int* __restrict__ glst,
    signed char* __restrict__ g8n)
{
    __shared__ double red[4 * 64 * 4];   // 8 KB

    const int t    = threadIdx.x;
    const int wq   = t >> 6;
    const int lane = t & 63;
    const int q    = lane >> 4;
    const int c    = lane & 15;

    const int g     = blockIdx.x;          // 0..1023
    const int btile = (g >> 3) & 7;
    const int nsup  = (g & 7) | ((g >> 6) << 3);   // 0..127
    const int n0    = nsup * 16;
    const int bcol  = btile * 16 + c;

    double4v pr = {0., 0., 0., 0.}, pcv = {0., 0., 0., 0.};
    pr  = __builtin_amdgcn_mfma_f64_16x16x4f64(0.25 * (double)c, 1.0, pr, 0, 0, 0);
    pcv = __builtin_amdgcn_mfma_f64_16x16x4f64(0.25, (double)c, pcv, 0, 0, 0);
    int rowD[4], colD[4];
    #pragma unroll
    for (int r = 0; r < 4; ++r) {
        rowD[r] = (int)(pr[r] + 0.25);
        colD[r] = (int)(pcv[r] + 0.25);
    }

    double4v acc[4] = {{0.,0.,0.,0.},{0.,0.,0.,0.},{0.,0.,0.,0.},{0.,0.,0.,0.}};

    const int    kbase = wq * (DD / 4);
    const float* wb0   = Wl + (size_t)(n0 + c) * DD + kbase + 4 * q;

    float4 wv0[4], sv[4];
    #pragma unroll
    for (int p = 0; p < 4; ++p) wv0[p] = *(const float4*)(wb0 + 16 * p);
    #pragma unroll
    for (int p = 0; p < 4; ++p) {
        int kabs = kbase + 16 * p + 4 * q;
        sv[p] = *(const float4*)(Atile + (size_t)(kabs >> 6) * 8192
                                 + bcol * 64 + (kabs & 63));
    }

    for (int u = 0; u < JBQ / 4; ++u) {
        #pragma unroll
        for (int gg = 0; gg < 4; ++gg) {
            float4 w0 = wv0[gg];
            float4 s  = sv[gg];

            int jn = 4 * u + 4 + gg; if (jn > JBQ - 1) jn = JBQ - 1;
            wv0[gg] = *(const float4*)(wb0 + 16 * jn);
            int kabs = kbase + 16 * jn + 4 * q;
            sv[gg] = *(const float4*)(Atile + (size_t)(kabs >> 6) * 8192
                                      + bcol * 64 + (kabs & 63));

            acc[0] = __builtin_amdgcn_mfma_f64_16x16x4f64((double)w0.x, (double)s.x, acc[0], 0, 0, 0);
            acc[1] = __builtin_amdgcn_mfma_f64_16x16x4f64((double)w0.y, (double)s.y, acc[1], 0, 0, 0);
            acc[2] = __builtin_amdgcn_mfma_f64_16x16x4f64((double)w0.z, (double)s.z, acc[2], 0, 0, 0);
            acc[3] = __builtin_amdgcn_mfma_f64_16x16x4f64((double)w0.w, (double)s.w, acc[3], 0, 0, 0);
        }
    }

    double4v a0 = (acc[0] + acc[1]) + (acc[2] + acc[3]);
    {
        double* my = red + ((size_t)wq * 64 + lane) * 4;
        #pragma unroll
        for (int r = 0; r < 4; ++r) my[r] = a0[r];
    }
    __syncthreads();
    if (wq == 0) {
        double a[4];
        #pragma unroll
        for (int r = 0; r < 4; ++r) {
            a[r] =  red[((size_t)0 * 64 + lane) * 4 + r];
            a[r] += red[((size_t)1 * 64 + lane) * 4 + r];
            a[r] += red[((size_t)2 * 64 + lane) * 4 + r];
            a[r] += red[((size_t)3 * 64 + lane) * 4 + r];
        }

        const double th = (double)thr[0];
        const int T = *Tptr;
        double m0 = 0., m1 = 0., m2 = 0., m3 = 0.;
        int c0 = 0, c1 = 0, c2 = 0, c3 = 0;
        for (int tt = 0; tt < T; ++tt) {
            m0 += a[0]; if (m0 > th) { c0++; m0 -= th; }
            m1 += a[1]; if (m1 > th) { c1++; m1 -= th; }
            m2 += a[2]; if (m2 > th) { c2++; m2 -= th; }
            m3 += a[3]; if (m3 > th) { c3++; m3 -= th; }
        }
        int cnt[4] = {c0, c1, c2, c3};
        #pragma unroll
        for (int r = 0; r < 4; ++r) {
            int n = n0 + rowD[r];
            int b = btile * 16 + colD[r];
            for (int j = goff[n]; j < goff[n + 1]; ++j) {
                int k = glst[j];
                g8n[(size_t)(k >> 6) * 8192 + b * 64 + (k & 63)] =
                    (signed char)cnt[r];
            }
        }
    }
}

// ---------------------------------------------------------------------------
// Integer-exact layer kernel (layers 1..3), R14-proven dual path:
// signed  => 4 signed base-256 planes, 4 chains (gfx950 measured path)
// unsigned=> 5 biased base-128 planes + ones-chain (fallback)
// ---------------------------------------------------------------------------
__global__ __launch_bounds__(256, 4) void layer_i8_kernel(
    const signed char* __restrict__ B8,    // g8 tiled [ck:32][b:128][kk:64]
    const signed char* __restrict__ Wd5,   // interleaved digit tiles
    const float* __restrict__ thr, int l,
    const int*   __restrict__ Tptr,
    const int* __restrict__ goff, const int* __restrict__ glst,
    signed char* __restrict__ g8n,
    const int* __restrict__ ooff, const int* __restrict__ olst,
    float* __restrict__ outp)
{
    __shared__ double red[4 * 64 * 4];   // 8 KB

    const int t    = threadIdx.x;
    const int wq   = t >> 6;
    const int lane = t & 63;
    const int q    = lane >> 4;
    const int c    = lane & 15;

    const int g     = blockIdx.x;          // 0..1023
    const int btile = (g >> 3) & 7;
    const int nsup  = (g & 7) | ((g >> 6) << 3);   // 0..127 (16-row tiles)
    const int n0    = nsup * 16;
    const int bcol  = btile * 16 + c;

    const int sgn = i8_probe_signed();

    // i8-native D-layout probe (R3-proven; signedness-agnostic: labels >= 0)
    int rowD[4], colD[4];
    {
        const int cb  = c * 0x01010101;
        const int hot = (q == 0) ? 1 : 0;
        int4v aLab = {cb, cb, cb, cb};
        int4v oneh = {hot, 0, 0, 0};
        int4v dR = {0, 0, 0, 0}, dC = {0, 0, 0, 0};
        dR = __builtin_amdgcn_mfma_i32_16x16x64_i8(aLab, oneh, dR, 0, 0, 0);
        dC = __builtin_amdgcn_mfma_i32_16x16x64_i8(oneh, aLab, dC, 0, 0, 0);
        #pragma unroll
        for (int r = 0; r < 4; ++r) { rowD[r] = dR[r]; colD[r] = dC[r]; }
    }

    int4v acc[NDIG], accS = (int4v)0;
    #pragma unroll
    for (int j = 0; j < NDIG; ++j) acc[j] = (int4v)0;

    const signed char* ab = Wd5 + (size_t)(nsup >> 1) * WD_NSUP
                          + (nsup & 1) * 1024 + c * 64 + q * 16;
    const signed char* bb = B8 + bcol * 64 + q * 16;

    const int4v ones = {0x01010101, 0x01010101, 0x01010101, 0x01010101};
    const int ck0 = wq * 8;

    if (sgn) {
        #pragma unroll 1
        for (int kc = 0; kc < 8; ++kc) {
            const signed char* ap = ab + (size_t)(ck0 + kc) * WD_KC;
            int4v A[NSGN], Bv;
            #pragma unroll
            for (int j = 0; j < NSGN; ++j)
                A[j] = *(const int4v*)(ap + (size_t)j * WD_J);
            Bv = *(const int4v*)(bb + (size_t)(ck0 + kc) * 8192);
            #pragma unroll
            for (int j = 0; j < NSGN; ++j)
                acc[j] = __builtin_amdgcn_mfma_i32_16x16x64_i8(A[j], Bv, acc[j], 0, 0, 0);
        }
        // recombine: sum_j acc_j * 2^(8j - 28)
        const double T0 = 0x1p-28, T1 = 0x1p-20, T2 = 0x1p-12, T3 = 0x1p-4;
        double* my = red + ((size_t)wq * 64 + lane) * 4;
        #pragma unroll
        for (int r = 0; r < 4; ++r)
            my[r] = T0 * (double)acc[0][r] + T1 * (double)acc[1][r]
                  + T2 * (double)acc[2][r] + T3 * (double)acc[3][r];
    } else {
        #pragma unroll 1
        for (int kc = 0; kc < 8; ++kc) {
            const signed char* ap = ab + (size_t)(ck0 + kc) * WD_KC;
            int4v A[NDIG], Bv;
            #pragma unroll
            for (int j = 0; j < NDIG; ++j)
                A[j] = *(const int4v*)(ap + (size_t)j * WD_J);
            Bv = *(const int4v*)(bb + (size_t)(ck0 + kc) * 8192);
            #pragma unroll
            for (int j = 0; j < NDIG; ++j)
                acc[j] = __builtin_amdgcn_mfma_i32_16x16x64_i8(A[j], Bv, acc[j], 0, 0, 0);
            accS = __builtin_amdgcn_mfma_i32_16x16x64_i8(ones, Bv, accS, 0, 0, 0);
        }
        const double S0 = 0x1p-33, S1 = 0x1p-26, S2 = 0x1p-19,
                     S3 = 0x1p-12, S4 = 0x1p-5;
        double* my = red + ((size_t)wq * 64 + lane) * 4;
        #pragma unroll
        for (int r = 0; r < 4; ++r)
            my[r] = S0 * (double)acc[0][r] + S1 * (double)acc[1][r]
                  + S2 * (double)acc[2][r] + S3 * (double)acc[3][r]
                  + S4 * (double)acc[4][r] - 2.0 * (double)accS[r];
    }
    __syncthreads();
    if (wq == 0) {
        double a[4];
        #pragma unroll
        for (int r = 0; r < 4; ++r) {
            a[r] =  red[((size_t)0 * 64 + lane) * 4 + r];
            a[r] += red[((size_t)1 * 64 + lane) * 4 + r];
            a[r] += red[((size_t)2 * 64 + lane) * 4 + r];
            a[r] += red[((size_t)3 * 64 + lane) * 4 + r];
        }

        const double th = (double)thr[l];
        const int T = *Tptr;
        const double invT = 1.0 / (double)T;
        double m0 = 0., m1 = 0., m2 = 0., m3 = 0.;
        int c0 = 0, c1 = 0, c2 = 0, c3 = 0;
        const double v0 = a[0] * invT, v1 = a[1] * invT,
                     v2 = a[2] * invT, v3 = a[3] * invT;
        for (int tt = 0; tt < T; ++tt) {
            m0 += v0; if (m0 > th) { c0++; m0 -= th; }
            m1 += v1; if (m1 > th) { c1++; m1 -= th; }
            m2 += v2; if (m2 > th) { c2++; m2 -= th; }
            m3 += v3; if (m3 > th) { c3++; m3 -= th; }
        }
        int cnt[4] = {c0, c1, c2, c3};
        #pragma unroll
        for (int r = 0; r < 4; ++r) {
            int n = n0 + rowD[r];
            int b = btile * 16 + colD[r];
            if (goff) {
                for (int j = goff[n]; j < goff[n + 1]; ++j) {
                    int k = glst[j];
                    g8n[(size_t)(k >> 6) * 8192 + b * 64 + (k & 63)] =
                        (signed char)cnt[r];
                }
            }
            if (ooff) {
                for (int j = ooff[n]; j < ooff[n + 1]; ++j)
                    outp[(size_t)b * OUTN + olst[j]] = (float)cnt[r];
            }
        }
    }
}

// ---------------------------------------------------------------------------
// Fallback fp64 layer kernel (small-ws path only; R7-proven, untouched).
// ---------------------------------------------------------------------------
__global__ __launch_bounds__(256, 2) void layer_kernel(
    const float* __restrict__ src,
    const int*   __restrict__ idx,
    int sR, int sB,
    const float* __restrict__ Wl,
    const float* __restrict__ thresholds, int l,
    const int*   __restrict__ Tptr,
    float* __restrict__ dst, int isLast)
{
    __shared__ double red[4 * 64 * 8];

    const int t    = threadIdx.x;
    const int wq   = t >> 6;
    const int lane = t & 63;
    const int q    = lane >> 4;
    const int c    = lane & 15;

    const int g     = blockIdx.x;
    const int btile = (g >> 3) & 7;
    const int nsup  = (g & 7) | ((g >> 6) << 3);
    const int n0    = nsup * 32;
    const int bcol  = btile * 16 + c;
    const size_t bo = (size_t)bcol * sB;

    double4v pr = {0., 0., 0., 0.}, pcv = {0., 0., 0., 0.};
    pr  = __builtin_amdgcn_mfma_f64_16x16x4f64(0.25 * (double)c, 1.0, pr, 0, 0, 0);
    pcv = __builtin_amdgcn_mfma_f64_16x16x4f64(0.25, (double)c, pcv, 0, 0, 0);
    int rowD[4], colD[4];
    #pragma unroll
    for (int r = 0; r < 4; ++r) {
        rowD[r] = (int)(pr[r] + 0.25);
        colD[r] = (int)(pcv[r] + 0.25);
    }

    double4v acc0[4] = {{0.,0.,0.,0.},{0.,0.,0.,0.},{0.,0.,0.,0.},{0.,0.,0.,0.}};
    double4v acc1[4] = {{0.,0.,0.,0.},{0.,0.,0.,0.},{0.,0.,0.,0.},{0.,0.,0.,0.}};

    const int    kbase = wq * (DD / 4);
    const float* wb0   = Wl + (size_t)(n0 + c) * DD + kbase + 4 * q;
    const float* wb1   = wb0 + (size_t)16 * DD;
    const int*   ibase = idx ? (idx + kbase + 4 * q) : nullptr;

    float4 wv0[4], wv1[4];
    float4 sv[4];
    int4   iv[4];

    #pragma unroll
    for (int p = 0; p < 4; ++p) {
        wv0[p] = *(const float4*)(wb0 + 16 * p);
        wv1[p] = *(const float4*)(wb1 + 16 * p);
    }
    #pragma unroll
    for (int p = 0; p < 4; ++p) {
        int r0, r1, r2, r3;
        if (ibase) {
            int4 iv0 = *(const int4*)(ibase + 16 * p);
            r0 = iv0.x; r1 = iv0.y; r2 = iv0.z; r3 = iv0.w;
        } else {
            int kb = kbase + 16 * p + 4 * q;
            r0 = kb; r1 = kb + 1; r2 = kb + 2; r3 = kb + 3;
        }
        sv[p].x = src[(size_t)r0 * sR + bo];
        sv[p].y = src[(size_t)r1 * sR + bo];
        sv[p].z = src[(size_t)r2 * sR + bo];
        sv[p].w = src[(size_t)r3 * sR + bo];
    }
    if (ibase) {
        #pragma unroll
        for (int p = 0; p < 4; ++p) iv[p] = *(const int4*)(ibase + 16 * (4 + p));
    }

    for (int u = 0; u < JBQ / 4; ++u) {
        #pragma unroll
        for (int gg = 0; gg < 4; ++gg) {
            float4 w0 = wv0[gg];
            float4 w1 = wv1[gg];
            float4 s  = sv[gg];

            int jn = 4 * u + 4 + gg; if (jn > JBQ - 1) jn = JBQ - 1;
            wv0[gg] = *(const float4*)(wb0 + 16 * jn);
            wv1[gg] = *(const float4*)(wb1 + 16 * jn);

            int r0, r1, r2, r3;
            if (ibase) {
                int4 ivv = iv[gg];
                r0 = ivv.x; r1 = ivv.y; r2 = ivv.z; r3 = ivv.w;
            } else {
                int kb = kbase + 16 * jn + 4 * q;
                r0 = kb; r1 = kb + 1; r2 = kb + 2; r3 = kb + 3;
            }
            sv[gg].x = src[(size_t)r0 * sR + bo];
            sv[gg].y = src[(size_t)r1 * sR + bo];
            sv[gg].z = src[(size_t)r2 * sR + bo];
            sv[gg].w = src[(size_t)r3 * sR + bo];

            if (ibase) {
                int jm = 4 * u + 8 + gg; if (jm > JBQ - 1) jm = JBQ - 1;
                iv[gg] = *(const int4*)(ibase + 16 * jm);
            }

            acc0[0] = __builtin_amdgcn_mfma_f64_16x16x4f64((double)w0.x, (double)s.x, acc0[0], 0, 0, 0);
            acc1[0] = __builtin_amdgcn_mfma_f64_16x16x4f64((double)w1.x, (double)s.x, acc1[0], 0, 0, 0);
            acc0[1] = __builtin_amdgcn_mfma_f64_16x16x4f64((double)w0.y, (double)s.y, acc0[1], 0, 0, 0);
            acc1[1] = __builtin_amdgcn_mfma_f64_16x16x4f64((double)w1.y, (double)s.y, acc1[1], 0, 0, 0);
            acc0[2] = __builtin_amdgcn_mfma_f64_16x16x4f64((double)w0.z, (double)s.z, acc0[2], 0, 0, 0);
            acc1[2] = __builtin_amdgcn_mfma_f64_16x16x4f64((double)w1.z, (double)s.z, acc1[2], 0, 0, 0);
            acc0[3] = __builtin_amdgcn_mfma_f64_16x16x4f64((double)w0.w, (double)s.w, acc0[3], 0, 0, 0);
            acc1[3] = __builtin_amdgcn_mfma_f64_16x16x4f64((double)w1.w, (double)s.w, acc1[3], 0, 0, 0);
        }
    }

    double4v a0 = (acc0[0] + acc0[1]) + (acc0[2] + acc0[3]);
    double4v a1 = (acc1[0] + acc1[1]) + (acc1[2] + acc1[3]);

    {
        double* my = red + ((size_t)wq * 64 + lane) * 8;
        #pragma unroll
        for (int r = 0; r < 4; ++r) { my[r] = a0[r]; my[4 + r] = a1[r]; }
    }
    __syncthreads();
    if (wq < 2) {
        const int off = wq * 4;
        double a[4];
        #pragma unroll
        for (int r = 0; r < 4; ++r) {
            a[r] =  red[((size_t)0 * 64 + lane) * 8 + off + r];
            a[r] += red[((size_t)1 * 64 + lane) * 8 + off + r];
            a[r] += red[((size_t)2 * 64 + lane) * 8 + off + r];
            a[r] += red[((size_t)3 * 64 + lane) * 8 + off + r];
        }

        const double th = (double)thresholds[l];
        const int T = *Tptr;
        const float sc = isLast ? 1.0f : (1.0f / (float)T);
        double m0 = 0., m1 = 0., m2 = 0., m3 = 0.;
        int c0 = 0, c1 = 0, c2 = 0, c3 = 0;
        for (int tt = 0; tt < T; ++tt) {
            m0 += a[0]; if (m0 > th) { c0++; m0 -= th; }
            m1 += a[1]; if (m1 > th) { c1++; m1 -= th; }
            m2 += a[2]; if (m2 > th) { c2++; m2 -= th; }
            m3 += a[3]; if (m3 > th) { c3++; m3 -= th; }
        }
        int cnt[4] = {c0, c1, c2, c3};
        #pragma unroll
        for (int r = 0; r < 4; ++r) {
            int n = n0 + 16 * wq + rowD[r];
            int b = btile * 16 + colD[r];
            dst[(size_t)n * BB + b] = (float)cnt[r] * sc;
        }
    }
}

__global__ __launch_bounds__(256) void out_kernel(
    const float* __restrict__ cntT, const int* __restrict__ out_idx,
    float* __restrict__ out)
{
    int i = blockIdx.x * 256 + threadIdx.x;
    int b = i >> 10;
    int o = i & 1023;
    out[i] = cntT[(size_t)out_idx[o] * BB + b];
}

extern "C" void kernel_launch(void* const* d_in, const int* in_sizes, int n_in,
                              void* d_out, int out_size, void* d_ws, size_t ws_size,
                              hipStream_t stream)
{
    const float* x    = (const float*)d_in[0];
    const float* W    = (const float*)d_in[1];
    const float* thr  = (const float*)d_in[2];
    const int*   axon = (const int*)d_in[3];
    const int*   oidx = (const int*)d_in[4];
    const int*   Tptr = (const int*)d_in[5];
    float* out = (float*)d_out;

    const size_t DP = (size_t)NN * DD;
    char* ws = (char*)d_ws;
    float* At   = (float*)ws;                         // 1 MB (tiled)
    float* mA   = (float*)(ws + (1u << 20));          // 1 MB (fallback)
    float* mB   = (float*)(ws + (2u << 20));          // 1 MB (fallback)
    float* cntT = (float*)(ws + (3u << 20));          // 1 MB (fallback)
    signed char* g8A = (signed char*)(ws + (4u << 20));               // 256 KB
    signed char* g8B = (signed char*)(ws + (4u << 20) + (256u << 10));// 256 KB
    int* off = (int*)(ws + (4u << 20) + (512u << 10));                // 33 KB
    int* lst = (int*)(ws + (4u << 20) + (640u << 10));                // 32 KB
    signed char* Wd  = (signed char*)(ws + (5u << 20));               // 60 MB

    const int useI8 = (ws_size >= ((size_t)80 << 20)) ? 1 : 0;

    if (!useI8) {
        const float* srcs[LL] = { x, mA, mB, mA };
        float*       dsts[LL] = { mA, mB, mA, cntT };
        for (int l = 0; l < LL; ++l) {
            layer_kernel<<<512, 256, 0, stream>>>(
                srcs[l], axon + (size_t)l * DD,
                (l == 0) ? 1 : BB, (l == 0) ? DD : 1,
                W + (size_t)l * NN * DD, thr, l, Tptr,
                dsts[l], (l == LL - 1) ? 1 : 0);
        }
        out_kernel<<<(BB * OUTN) / 256, 256, 0, stream>>>(cntT, oidx, out);
        return;
    }

    // 1) prep: wdig(bit-trick digitization) + tiled-At + CSR maps
    prep_kernel<<<NWDIG + NG0 + NCSR, 256, 0, stream>>>(
        W + DP, x, axon, oidx, Wd, At, off, lst);

    // 2) layer 0: fp64 path on tiled At; scatter counts -> g8A
    layer0_kernel<<<1024, 256, 0, stream>>>(
        At, W, thr, Tptr, off + 0 * 2052, lst + 0 * 2048, g8A);

    // 3-5) layers 1..3: signed i8 path; scatter to next g8 / out
    layer_i8_kernel<<<1024, 256, 0, stream>>>(
        g8A, Wd + 0 * 5 * DP, thr, 1, Tptr,
        off + 1 * 2052, lst + 1 * 2048, g8B,
        nullptr, nullptr, nullptr);
    layer_i8_kernel<<<1024, 256, 0, stream>>>(
        g8B, Wd + 1 * 5 * DP, thr, 2, Tptr,
        off + 2 * 2052, lst + 2 * 2048, g8A,
        nullptr, nullptr, nullptr);
    layer_i8_kernel<<<1024, 256, 0, stream>>>(
        g8A, Wd + 2 * 5 * DP, thr, 3, Tptr,
        nullptr, nullptr, nullptr,
        off + 3 * 2052, lst + 3 * 2048, out);
}

// Round 17
// 198.739 us; speedup vs baseline: 1.0432x; 1.0432x over previous
//
#include <hip/hip_runtime.h>

// Problem constants
#define BB   128
#define DD   2048
#define NN   2048
#define LL   4
#define OUTN 1024
#define NDIG 5                 // unsigned-mode planes (dead on gfx950, kept)
#define NSGN 4                 // signed W planes (base-256, scale 2^-28)
#define NXP  3                 // signed x planes (base-256, scale 2^-22)

#define NWDIG 4096             // wdig blocks: 4 layers x 32 nchunk x 32 kchunk
#define NG0   1024             // x-digitizer blocks: DD*BB/256
#define NCSR  4                // inverse-map builds (axon1..3, out_idx)

// Wd layout (R13-proven): [l][nsup:64][kc:32][j:5][cc:32][kk:64]
#define WD_NSUP 327680
#define WD_KC   10240
#define WD_J    2048
#define XPLANE  262144         // xd plane stride (256 KB)

typedef double double4v __attribute__((ext_vector_type(4)));
typedef int    int4v    __attribute__((ext_vector_type(4)));
typedef char   char4v   __attribute__((ext_vector_type(4)));
typedef char   char16v  __attribute__((ext_vector_type(16)));

// ---------------------------------------------------------------------------
// Runtime i8-MFMA signedness probe (R14-proven: gfx950 is SIGNED).
// ---------------------------------------------------------------------------
__device__ __forceinline__ int i8_probe_signed()
{
    const int lane = threadIdx.x & 63;
    const int hot  = ((lane >> 4) == 0) ? 1 : 0;
    int4v aFF  = {-1, -1, -1, -1};
    int4v oneh = {hot, 0, 0, 0};
    int4v d    = {0, 0, 0, 0};
    d = __builtin_amdgcn_mfma_i32_16x16x64_i8(aFF, oneh, d, 0, 0, 0);
    return d[0] < 0;
}

// ---------------------------------------------------------------------------
// PREP kernel (one launch): blockIdx-partitioned independent producers.
//  [0, NWDIG)      : W digitization for ALL 4 layers (R15 bit-trick).
//  [NWDIG, +NG0)   : x-digitizer.  R17 FIX: scale 2^22 (was 2^23, which
//                    OVERFLOWED the 3-digit balanced range 127*(1+256+65536)
//                    = 8355711 < 2^23 for x > 0.996 -- dropped carry made
//                    x_hat = x-2 for ~0.4% of entries => R16's absmax 64).
//                    V = rintf(x*2^22) <= 2^22 fits safely.
//  [NWDIG+NG0, +4) : CSR inverse maps (R7-proven)
// ---------------------------------------------------------------------------
__global__ __launch_bounds__(256) void prep_kernel(
    const float* __restrict__ W,       // all 4 layers
    const float* __restrict__ x,
    const int*   __restrict__ axon,
    const int*   __restrict__ oidx,
    signed char* __restrict__ Wd,
    signed char* __restrict__ xd,      // 3 planes x 256 KB
    int*         __restrict__ off,     // [4][2052]
    int*         __restrict__ lst)     // [4][2048]
{
    __shared__ int hist[2048];
    __shared__ int part[256];

    const int t  = threadIdx.x;
    const int bk = blockIdx.x;
    const size_t DP = (size_t)NN * DD;

    if (bk < NWDIG) {
        // ---- W digitization, wide stores, bit-trick (R15-proven) ----
        const int l   = bk >> 10;            // layer 0..3
        const int rem = bk & 1023;
        const int nc  = rem >> 5;            // n-chunk 0..31 (64 rows each)
        const int kc  = rem & 31;            // k-chunk 0..31 (64 cols each)
        const int n   = nc * 64 + (t >> 2);
        const int k   = kc * 64 + (t & 3) * 16;

        const float* wp = W + (size_t)l * DP + (size_t)n * DD + k;
        float wv[16];
        #pragma unroll
        for (int p = 0; p < 4; ++p) {
            float4 w = *(const float4*)(wp + 4 * p);
            wv[4 * p + 0] = w.x; wv[4 * p + 1] = w.y;
            wv[4 * p + 2] = w.z; wv[4 * p + 3] = w.w;
        }
        signed char* base = Wd + (size_t)l * 5 * DP
                          + (size_t)(n >> 5) * WD_NSUP + (size_t)kc * WD_KC
                          + (n & 31) * 64 + (k & 63);

        const int sgn = i8_probe_signed();
        if (sgn) {
            int X[16];
            #pragma unroll
            for (int e = 0; e < 16; ++e) {
                int V = (int)rintf(wv[e] * 0x1p28f);
                X[e] = (int)(((unsigned)V + 0x80808080u) ^ 0x80808080u);
            }
            #pragma unroll
            for (int j = 0; j < NSGN; ++j) {
                char16v p;
                #pragma unroll
                for (int e = 0; e < 16; ++e)
                    p[e] = (char)((X[e] >> (8 * j)) & 255);
                *(char16v*)(base + (size_t)j * WD_J) = p;
            }
        } else {
            // unsigned fallback (never taken on gfx950)
            unsigned long long V[16];
            #pragma unroll
            for (int e = 0; e < 16; ++e)
                V[e] = (unsigned long long)(__double2ll_rn((double)wv[e] * 0x1p33)
                                            + (1LL << 34));
            #pragma unroll
            for (int j = 0; j < NDIG; ++j) {
                char16v p;
                #pragma unroll
                for (int e = 0; e < 16; ++e)
                    p[e] = (char)((V[e] >> (7 * j)) & 127);
                *(char16v*)(base + (size_t)j * WD_J) = p;
            }
        }
        return;
    }
    if (bk < NWDIG + NG0) {
        // ---- x-digitizer into tiled planes (R17: scale 2^22, no overflow) --
        int i = (bk - NWDIG) * 256 + t;            // over BB*DD
        int b = i >> 11;
        int k = i & (DD - 1);
        int V = (int)rintf(x[b * DD + axon[k]] * 0x1p22f);   // <= 2^22, fits
        unsigned X = ((unsigned)V + 0x808080u) ^ 0x808080u;
        size_t pos = (size_t)(k >> 6) * 8192 + b * 64 + (k & 63);
        xd[pos]              = (signed char)(X & 255);
        xd[XPLANE + pos]     = (signed char)((X >> 8) & 255);
        xd[2 * XPLANE + pos] = (signed char)((X >> 16) & 255);
        return;
    }
    // ---- CSR inverse-map build (4 blocks, R7-proven) ----
    {
        const int m   = bk - (NWDIG + NG0);
        const int* ip = (m < 3) ? (axon + (size_t)(m + 1) * DD) : oidx;
        const int cnt = (m < 3) ? DD : OUTN;
        int* offG = off + m * 2052;
        int* lstG = lst + m * 2048;

        for (int i = t; i < 2048; i += 256) hist[i] = 0;
        __syncthreads();
        for (int e = t; e < cnt; e += 256) atomicAdd(&hist[ip[e]], 1);
        __syncthreads();

        const int b0 = t * 8;
        int s = 0;
        #pragma unroll
        for (int i = 0; i < 8; ++i) s += hist[b0 + i];
        part[t] = s;
        __syncthreads();
        for (int d = 1; d < 256; d <<= 1) {
            int v = (t >= d) ? part[t - d] : 0;
            __syncthreads();
            part[t] += v;
            __syncthreads();
        }
        int base = part[t] - s;
        #pragma unroll
        for (int i = 0; i < 8; ++i) {
            int h = hist[b0 + i];
            offG[b0 + i] = base;
            hist[b0 + i] = base;
            base += h;
        }
        if (t == 255) offG[2048] = base;
        __syncthreads();
        for (int e = t; e < cnt; e += 256) {
            int n = ip[e];
            int pos = atomicAdd(&hist[n], 1);
            lstG[pos] = e;
        }
    }
}

// ---------------------------------------------------------------------------
// Layer 0, R17: signed-i8 digit GEMM (replaces the 45us fp64 path).
// A = 4 W-digit planes (2^-28), B = 3 x-digit planes (2^-22):
//   sum_k W*x = sum_{i,j} 2^(8(i+j)-50) * acc_ij   (12 exact i32 chains).
// Worst-case error ~1.4e-5 (x-quant 1e-5 + W-quant 3.8e-6) -- same band as
// the fp32 reference itself; worst case one +-1 spike flip (1.0 < 1.28).
// Structure/probe/scatter = layer_i8-proven.  Signed-only (R14-measured).
// ---------------------------------------------------------------------------
__global__ __launch_bounds__(256, 4) void layer0_i8_kernel(
    const signed char* __restrict__ xd,    // 3 tiled planes
    const signed char* __restrict__ Wd0,   // layer-0 digit tiles
    const float* __restrict__ thr,
    const int*   __restrict__ Tptr,
    const int* __restrict__ goff, const int* __restrict__ glst,
    signed char* __restrict__ g8n)
{
    __shared__ double red[4 * 64 * 4];   // 8 KB

    const int t    = threadIdx.x;
    const int wq   = t >> 6;
    const int lane = t & 63;
    const int q    = lane >> 4;
    const int c    = lane & 15;

    const int g     = blockIdx.x;          // 0..1023
    const int btile = (g >> 3) & 7;
    const int nsup  = (g & 7) | ((g >> 6) << 3);   // 0..127 (16-row tiles)
    const int n0    = nsup * 16;
    const int bcol  = btile * 16 + c;

    // i8-native D-layout probe (R3-proven)
    int rowD[4], colD[4];
    {
        const int cb  = c * 0x01010101;
        const int hot = (q == 0) ? 1 : 0;
        int4v aLab = {cb, cb, cb, cb};
        int4v oneh = {hot, 0, 0, 0};
        int4v dR = {0, 0, 0, 0}, dC = {0, 0, 0, 0};
        dR = __builtin_amdgcn_mfma_i32_16x16x64_i8(aLab, oneh, dR, 0, 0, 0);
        dC = __builtin_amdgcn_mfma_i32_16x16x64_i8(oneh, aLab, dC, 0, 0, 0);
        #pragma unroll
        for (int r = 0; r < 4; ++r) { rowD[r] = dR[r]; colD[r] = dC[r]; }
    }

    int4v acc[NSGN * NXP];
    #pragma unroll
    for (int j = 0; j < NSGN * NXP; ++j) acc[j] = (int4v)0;

    const signed char* ab = Wd0 + (size_t)(nsup >> 1) * WD_NSUP
                          + (nsup & 1) * 1024 + c * 64 + q * 16;
    const signed char* xb = xd + bcol * 64 + q * 16;

    const int ck0 = wq * 8;

    #pragma unroll 1
    for (int kc = 0; kc < 8; ++kc) {
        const signed char* ap = ab + (size_t)(ck0 + kc) * WD_KC;
        const signed char* bp = xb + (size_t)(ck0 + kc) * 8192;
        int4v A[NSGN], Bv[NXP];
        #pragma unroll
        for (int i = 0; i < NSGN; ++i)
            A[i] = *(const int4v*)(ap + (size_t)i * WD_J);
        #pragma unroll
        for (int j = 0; j < NXP; ++j)
            Bv[j] = *(const int4v*)(bp + (size_t)j * XPLANE);
        #pragma unroll
        for (int i = 0; i < NSGN; ++i)
            #pragma unroll
            for (int j = 0; j < NXP; ++j)
                acc[i * NXP + j] = __builtin_amdgcn_mfma_i32_16x16x64_i8(
                    A[i], Bv[j], acc[i * NXP + j], 0, 0, 0);
    }

    // recombine: weights 2^(8(i+j) - 50)   (2^-28 W-scale * 2^-22 x-scale)
    const double Wt[6] = {0x1p-50, 0x1p-42, 0x1p-34, 0x1p-26, 0x1p-18, 0x1p-10};
    {
        double* my = red + ((size_t)wq * 64 + lane) * 4;
        #pragma unroll
        for (int r = 0; r < 4; ++r) {
            double s = 0.;
            #pragma unroll
            for (int i = 0; i < NSGN; ++i)
                #pragma unroll
                for (int j = 0; j < NXP; ++j)
                    s += Wt[i + j] * (double)acc[i * NXP + j][r];
            my[r] = s;
        }
    }
    __syncthreads();
    if (wq == 0) {
        double a[4];
        #pragma unroll
        for (int r = 0; r < 4; ++r) {
            a[r] =  red[((size_t)0 * 64 + lane) * 4 + r];
            a[r] += red[((size_t)1 * 64 + lane) * 4 + r];
            a[r] += red[((size_t)2 * 64 + lane) * 4 + r];
            a[r] += red[((size_t)3 * 64 + lane) * 4 + r];
        }

        const double th = (double)thr[0];
        const int T = *Tptr;
        double m0 = 0., m1 = 0., m2 = 0., m3 = 0.;
        int c0 = 0, c1 = 0, c2 = 0, c3 = 0;
        for (int tt = 0; tt < T; ++tt) {      // layer-0 avg = sum W*x (no /T)
            m0 += a[0]; if (m0 > th) { c0++; m0 -= th; }
            m1 += a[1]; if (m1 > th) { c1++; m1 -= th; }
            m2 += a[2]; if (m2 > th) { c2++; m2 -= th; }
            m3 += a[3]; if (m3 > th) { c3++; m3 -= th; }
        }
        int cnt[4] = {c0, c1, c2, c3};
        #pragma unroll
        for (int r = 0; r < 4; ++r) {
            int n = n0 + rowD[r];
            int b = btile * 16 + colD[r];
            for (int j = goff[n]; j < goff[n + 1]; ++j) {
                int k = glst[j];
                g8n[(size_t)(k >> 6) * 8192 + b * 64 + (k & 63)] =
                    (signed char)cnt[r];
            }
        }
    }
}

// ---------------------------------------------------------------------------
// Integer-exact layer kernel (layers 1..3): byte-identical to R15 (proven).
// ---------------------------------------------------------------------------
__global__ __launch_bounds__(256, 4) void layer_i8_kernel(
    const signed char* __restrict__ B8,    // g8 tiled [ck:32][b:128][kk:64]
    const signed char* __restrict__ Wd5,   // interleaved digit tiles
    const float* __restrict__ thr, int l,
    const int*   __restrict__ Tptr,
    const int* __restrict__ goff, const int* __restrict__ glst,
    signed char* __restrict__ g8n,
    const int* __restrict__ ooff, const int* __restrict__ olst,
    float* __restrict__ outp)
{
    __shared__ double red[4 * 64 * 4];   // 8 KB

    const int t    = threadIdx.x;
    const int wq   = t >> 6;
    const int lane = t & 63;
    const int q    = lane >> 4;
    const int c    = lane & 15;

    const int g     = blockIdx.x;          // 0..1023
    const int btile = (g >> 3) & 7;
    const int nsup  = (g & 7) | ((g >> 6) << 3);   // 0..127 (16-row tiles)
    const int n0    = nsup * 16;
    const int bcol  = btile * 16 + c;

    const int sgn = i8_probe_signed();

    int rowD[4], colD[4];
    {
        const int cb  = c * 0x01010101;
        const int hot = (q == 0) ? 1 : 0;
        int4v aLab = {cb, cb, cb, cb};
        int4v oneh = {hot, 0, 0, 0};
        int4v dR = {0, 0, 0, 0}, dC = {0, 0, 0, 0};
        dR = __builtin_amdgcn_mfma_i32_16x16x64_i8(aLab, oneh, dR, 0, 0, 0);
        dC = __builtin_amdgcn_mfma_i32_16x16x64_i8(oneh, aLab, dC, 0, 0, 0);
        #pragma unroll
        for (int r = 0; r < 4; ++r) { rowD[r] = dR[r]; colD[r] = dC[r]; }
    }

    int4v acc[NDIG], accS = (int4v)0;
    #pragma unroll
    for (int j = 0; j < NDIG; ++j) acc[j] = (int4v)0;

    const signed char* ab = Wd5 + (size_t)(nsup >> 1) * WD_NSUP
                          + (nsup & 1) * 1024 + c * 64 + q * 16;
    const signed char* bb = B8 + bcol * 64 + q * 16;

    const int4v ones = {0x01010101, 0x01010101, 0x01010101, 0x01010101};
    const int ck0 = wq * 8;

    if (sgn) {
        #pragma unroll 1
        for (int kc = 0; kc < 8; ++kc) {
            const signed char* ap = ab + (size_t)(ck0 + kc) * WD_KC;
            int4v A[NSGN], Bv;
            #pragma unroll
            for (int j = 0; j < NSGN; ++j)
                A[j] = *(const int4v*)(ap + (size_t)j * WD_J);
            Bv = *(const int4v*)(bb + (size_t)(ck0 + kc) * 8192);
            #pragma unroll
            for (int j = 0; j < NSGN; ++j)
                acc[j] = __builtin_amdgcn_mfma_i32_16x16x64_i8(A[j], Bv, acc[j], 0, 0, 0);
        }
        const double T0 = 0x1p-28, T1 = 0x1p-20, T2 = 0x1p-12, T3 = 0x1p-4;
        double* my = red + ((size_t)wq * 64 + lane) * 4;
        #pragma unroll
        for (int r = 0; r < 4; ++r)
            my[r] = T0 * (double)acc[0][r] + T1 * (double)acc[1][r]
                  + T2 * (double)acc[2][r] + T3 * (double)acc[3][r];
    } else {
        #pragma unroll 1
        for (int kc = 0; kc < 8; ++kc) {
            const signed char* ap = ab + (size_t)(ck0 + kc) * WD_KC;
            int4v A[NDIG], Bv;
            #pragma unroll
            for (int j = 0; j < NDIG; ++j)
                A[j] = *(const int4v*)(ap + (size_t)j * WD_J);
            Bv = *(const int4v*)(bb + (size_t)(ck0 + kc) * 8192);
            #pragma unroll
            for (int j = 0; j < NDIG; ++j)
                acc[j] = __builtin_amdgcn_mfma_i32_16x16x64_i8(A[j], Bv, acc[j], 0, 0, 0);
            accS = __builtin_amdgcn_mfma_i32_16x16x64_i8(ones, Bv, accS, 0, 0, 0);
        }
        const double S0 = 0x1p-33, S1 = 0x1p-26, S2 = 0x1p-19,
                     S3 = 0x1p-12, S4 = 0x1p-5;
        double* my = red + ((size_t)wq * 64 + lane) * 4;
        #pragma unroll
        for (int r = 0; r < 4; ++r)
            my[r] = S0 * (double)acc[0][r] + S1 * (double)acc[1][r]
                  + S2 * (double)acc[2][r] + S3 * (double)acc[3][r]
                  + S4 * (double)acc[4][r] - 2.0 * (double)accS[r];
    }
    __syncthreads();
    if (wq == 0) {
        double a[4];
        #pragma unroll
        for (int r = 0; r < 4; ++r) {
            a[r] =  red[((size_t)0 * 64 + lane) * 4 + r];
            a[r] += red[((size_t)1 * 64 + lane) * 4 + r];
            a[r] += red[((size_t)2 * 64 + lane) * 4 + r];
            a[r] += red[((size_t)3 * 64 + lane) * 4 + r];
        }

        const double th = (double)thr[l];
        const int T = *Tptr;
        const double invT = 1.0 / (double)T;
        double m0 = 0., m1 = 0., m2 = 0., m3 = 0.;
        int c0 = 0, c1 = 0, c2 = 0, c3 = 0;
        const double v0 = a[0] * invT, v1 = a[1] * invT,
                     v2 = a[2] * invT, v3 = a[3] * invT;
        for (int tt = 0; tt < T; ++tt) {
            m0 += v0; if (m0 > th) { c0++; m0 -= th; }
            m1 += v1; if (m1 > th) { c1++; m1 -= th; }
            m2 += v2; if (m2 > th) { c2++; m2 -= th; }
            m3 += v3; if (m3 > th) { c3++; m3 -= th; }
        }
        int cnt[4] = {c0, c1, c2, c3};
        #pragma unroll
        for (int r = 0; r < 4; ++r) {
            int n = n0 + rowD[r];
            int b = btile * 16 + colD[r];
            if (goff) {
                for (int j = goff[n]; j < goff[n + 1]; ++j) {
                    int k = glst[j];
                    g8n[(size_t)(k >> 6) * 8192 + b * 64 + (k & 63)] =
                        (signed char)cnt[r];
                }
            }
            if (ooff) {
                for (int j = ooff[n]; j < ooff[n + 1]; ++j)
                    outp[(size_t)b * OUTN + olst[j]] = (float)cnt[r];
            }
        }
    }
}

// ---------------------------------------------------------------------------
// Fallback fp64 layer kernel (small-ws path only; R7-proven, untouched).
// ---------------------------------------------------------------------------
__global__ __launch_bounds__(256, 2) void layer_kernel(
    const float* __restrict__ src,
    const int*   __restrict__ idx,
    int sR, int sB,
    const float* __restrict__ Wl,
    const float* __restrict__ thresholds, int l,
    const int*   __restrict__ Tptr,
    float* __restrict__ dst, int isLast)
{
    __shared__ double red[4 * 64 * 8];

    const int t    = threadIdx.x;
    const int wq   = t >> 6;
    const int lane = t & 63;
    const int q    = lane >> 4;
    const int c    = lane & 15;

    const int g     = blockIdx.x;
    const int btile = (g >> 3) & 7;
    const int nsup  = (g & 7) | ((g >> 6) << 3);
    const int n0    = nsup * 32;
    const int bcol  = btile * 16 + c;
    const size_t bo = (size_t)bcol * sB;

    double4v pr = {0., 0., 0., 0.}, pcv = {0., 0., 0., 0.};
    pr  = __builtin_amdgcn_mfma_f64_16x16x4f64(0.25 * (double)c, 1.0, pr, 0, 0, 0);
    pcv = __builtin_amdgcn_mfma_f64_16x16x4f64(0.25, (double)c, pcv, 0, 0, 0);
    int rowD[4], colD[4];
    #pragma unroll
    for (int r = 0; r < 4; ++r) {
        rowD[r] = (int)(pr[r] + 0.25);
        colD[r] = (int)(pcv[r] + 0.25);
    }

    double4v acc0[4] = {{0.,0.,0.,0.},{0.,0.,0.,0.},{0.,0.,0.,0.},{0.,0.,0.,0.}};
    double4v acc1[4] = {{0.,0.,0.,0.},{0.,0.,0.,0.},{0.,0.,0.,0.},{0.,0.,0.,0.}};

    const int    kbase = wq * (DD / 4);
    const float* wb0   = Wl + (size_t)(n0 + c) * DD + kbase + 4 * q;
    const float* wb1   = wb0 + (size_t)16 * DD;
    const int*   ibase = idx ? (idx + kbase + 4 * q) : nullptr;

    float4 wv0[4], wv1[4];
    float4 sv[4];
    int4   iv[4];

    #pragma unroll
    for (int p = 0; p < 4; ++p) {
        wv0[p] = *(const float4*)(wb0 + 16 * p);
        wv1[p] = *(const float4*)(wb1 + 16 * p);
    }
    #pragma unroll
    for (int p = 0; p < 4; ++p) {
        int r0, r1, r2, r3;
        if (ibase) {
            int4 iv0 = *(const int4*)(ibase + 16 * p);
            r0 = iv0.x; r1 = iv0.y; r2 = iv0.z; r3 = iv0.w;
        } else {
            int kb = kbase + 16 * p + 4 * q;
            r0 = kb; r1 = kb + 1; r2 = kb + 2; r3 = kb + 3;
        }
        sv[p].x = src[(size_t)r0 * sR + bo];
        sv[p].y = src[(size_t)r1 * sR + bo];
        sv[p].z = src[(size_t)r2 * sR + bo];
        sv[p].w = src[(size_t)r3 * sR + bo];
    }
    if (ibase) {
        #pragma unroll
        for (int p = 0; p < 4; ++p) iv[p] = *(const int4*)(ibase + 16 * (4 + p));
    }

    for (int u = 0; u < 8; ++u) {
        #pragma unroll
        for (int gg = 0; gg < 4; ++gg) {
            float4 w0 = wv0[gg];
            float4 w1 = wv1[gg];
            float4 s  = sv[gg];

            int jn = 4 * u + 4 + gg; if (jn > 31) jn = 31;
            wv0[gg] = *(const float4*)(wb0 + 16 * jn);
            wv1[gg] = *(const float4*)(wb1 + 16 * jn);

            int r0, r1, r2, r3;
            if (ibase) {
                int4 ivv = iv[gg];
                r0 = ivv.x; r1 = ivv.y; r2 = ivv.z; r3 = ivv.w;
            } else {
                int kb = kbase + 16 * jn + 4 * q;
                r0 = kb; r1 = kb + 1; r2 = kb + 2; r3 = kb + 3;
            }
            sv[gg].x = src[(size_t)r0 * sR + bo];
            sv[gg].y = src[(size_t)r1 * sR + bo];
            sv[gg].z = src[(size_t)r2 * sR + bo];
            sv[gg].w = src[(size_t)r3 * sR + bo];

            if (ibase) {
                int jm = 4 * u + 8 + gg; if (jm > 31) jm = 31;
                iv[gg] = *(const int4*)(ibase + 16 * jm);
            }

            acc0[0] = __builtin_amdgcn_mfma_f64_16x16x4f64((double)w0.x, (double)s.x, acc0[0], 0, 0, 0);
            acc1[0] = __builtin_amdgcn_mfma_f64_16x16x4f64((double)w1.x, (double)s.x, acc1[0], 0, 0, 0);
            acc0[1] = __builtin_amdgcn_mfma_f64_16x16x4f64((double)w0.y, (double)s.y, acc0[1], 0, 0, 0);
            acc1[1] = __builtin_amdgcn_mfma_f64_16x16x4f64((double)w1.y, (double)s.y, acc1[1], 0, 0, 0);
            acc0[2] = __builtin_amdgcn_mfma_f64_16x16x4f64((double)w0.z, (double)s.z, acc0[2], 0, 0, 0);
            acc1[2] = __builtin_amdgcn_mfma_f64_16x16x4f64((double)w1.z, (double)s.z, acc1[2], 0, 0, 0);
            acc0[3] = __builtin_amdgcn_mfma_f64_16x16x4f64((double)w0.w, (double)s.w, acc0[3], 0, 0, 0);
            acc1[3] = __builtin_amdgcn_mfma_f64_16x16x4f64((double)w1.w, (double)s.w, acc1[3], 0, 0, 0);
        }
    }

    double4v a0 = (acc0[0] + acc0[1]) + (acc0[2] + acc0[3]);
    double4v a1 = (acc1[0] + acc1[1]) + (acc1[2] + acc1[3]);

    {
        double* my = red + ((size_t)wq * 64 + lane) * 8;
        #pragma unroll
        for (int r = 0; r < 4; ++r) { my[r] = a0[r]; my[4 + r] = a1[r]; }
    }
    __syncthreads();
    if (wq < 2) {
        const int off = wq * 4;
        double a[4];
        #pragma unroll
        for (int r = 0; r < 4; ++r) {
            a[r] =  red[((size_t)0 * 64 + lane) * 8 + off + r];
            a[r] += red[((size_t)1 * 64 + lane) * 8 + off + r];
            a[r] += red[((size_t)2 * 64 + lane) * 8 + off + r];
            a[r] += red[((size_t)3 * 64 + lane) * 8 + off + r];
        }

        const double th = (double)thresholds[l];
        const int T = *Tptr;
        const float sc = isLast ? 1.0f : (1.0f / (float)T);
        double m0 = 0., m1 = 0., m2 = 0., m3 = 0.;
        int c0 = 0, c1 = 0, c2 = 0, c3 = 0;
        for (int tt = 0; tt < T; ++tt) {
            m0 += a[0]; if (m0 > th) { c0++; m0 -= th; }
            m1 += a[1]; if (m1 > th) { c1++; m1 -= th; }
            m2 += a[2]; if (m2 > th) { c2++; m2 -= th; }
            m3 += a[3]; if (m3 > th) { c3++; m3 -= th; }
        }
        int cnt[4] = {c0, c1, c2, c3};
        #pragma unroll
        for (int r = 0; r < 4; ++r) {
            int n = n0 + 16 * wq + rowD[r];
            int b = btile * 16 + colD[r];
            dst[(size_t)n * BB + b] = (float)cnt[r] * sc;
        }
    }
}

__global__ __launch_bounds__(256) void out_kernel(
    const float* __restrict__ cntT, const int* __restrict__ out_idx,
    float* __restrict__ out)
{
    int i = blockIdx.x * 256 + threadIdx.x;
    int b = i >> 10;
    int o = i & 1023;
    out[i] = cntT[(size_t)out_idx[o] * BB + b];
}

extern "C" void kernel_launch(void* const* d_in, const int* in_sizes, int n_in,
                              void* d_out, int out_size, void* d_ws, size_t ws_size,
                              hipStream_t stream)
{
    const float* x    = (const float*)d_in[0];
    const float* W    = (const float*)d_in[1];
    const float* thr  = (const float*)d_in[2];
    const int*   axon = (const int*)d_in[3];
    const int*   oidx = (const int*)d_in[4];
    const int*   Tptr = (const int*)d_in[5];
    float* out = (float*)d_out;

    const size_t DP = (size_t)NN * DD;
    char* ws = (char*)d_ws;
    signed char* xd = (signed char*)ws;               // 768 KB (3 planes)
    float* mA   = (float*)(ws + (1u << 20));          // 1 MB (fallback)
    float* mB   = (float*)(ws + (2u << 20));          // 1 MB (fallback)
    float* cntT = (float*)(ws + (3u << 20));          // 1 MB (fallback)
    signed char* g8A = (signed char*)(ws + (4u << 20));               // 256 KB
    signed char* g8B = (signed char*)(ws + (4u << 20) + (256u << 10));// 256 KB
    int* off = (int*)(ws + (4u << 20) + (512u << 10));                // 33 KB
    int* lst = (int*)(ws + (4u << 20) + (640u << 10));                // 32 KB
    signed char* Wd  = (signed char*)(ws + (5u << 20));               // 80 MB (4 layers)

    const int useI8 = (ws_size >= ((size_t)96 << 20)) ? 1 : 0;

    if (!useI8) {
        const float* srcs[LL] = { x, mA, mB, mA };
        float*       dsts[LL] = { mA, mB, mA, cntT };
        for (int l = 0; l < LL; ++l) {
            layer_kernel<<<512, 256, 0, stream>>>(
                srcs[l], axon + (size_t)l * DD,
                (l == 0) ? 1 : BB, (l == 0) ? DD : 1,
                W + (size_t)l * NN * DD, thr, l, Tptr,
                dsts[l], (l == LL - 1) ? 1 : 0);
        }
        out_kernel<<<(BB * OUTN) / 256, 256, 0, stream>>>(cntT, oidx, out);
        return;
    }

    // 1) prep: wdig(4 layers) + x-digitizer(2^22, overflow-safe) + CSR maps
    prep_kernel<<<NWDIG + NG0 + NCSR, 256, 0, stream>>>(
        W, x, axon, oidx, Wd, xd, off, lst);

    // 2) layer 0: signed-i8 digit GEMM (x-digits x W-digits) -> g8A
    layer0_i8_kernel<<<1024, 256, 0, stream>>>(
        xd, Wd + 0 * 5 * DP, thr, Tptr,
        off + 0 * 2052, lst + 0 * 2048, g8A);

    // 3-5) layers 1..3: proven i8 path; scatter to next g8 / out
    layer_i8_kernel<<<1024, 256, 0, stream>>>(
        g8A, Wd + 1 * 5 * DP, thr, 1, Tptr,
        off + 1 * 2052, lst + 1 * 2048, g8B,
        nullptr, nullptr, nullptr);
    layer_i8_kernel<<<1024, 256, 0, stream>>>(
        g8B, Wd + 2 * 5 * DP, thr, 2, Tptr,
        off + 2 * 2052, lst + 2 * 2048, g8A,
        nullptr, nullptr, nullptr);
    layer_i8_kernel<<<1024, 256, 0, stream>>>(
        g8A, Wd + 3 * 5 * DP, thr, 3, Tptr,
        nullptr, nullptr, nullptr,
        off + 3 * 2052, lst + 3 * 2048, out);
}